// Round 9
// baseline (231.265 us; speedup 1.0000x reference)
//
#include <hip/hip_runtime.h>
#include <hip/hip_bf16.h>

#define DIMC 512
#define LEN  2048
#define NH   16
#define HD   32
#define RR   32

typedef __bf16 bf8_t __attribute__((ext_vector_type(8)));
typedef float  f4_t  __attribute__((ext_vector_type(4)));

__device__ __forceinline__ void gload16(const void* g, void* l) {
    __builtin_amdgcn_global_load_lds(
        (const __attribute__((address_space(1))) unsigned int*)g,
        (__attribute__((address_space(3))) unsigned int*)l, 16, 0, 0);
}

__device__ __forceinline__ int fswz(int col) {
    return (col ^ (col >> 2) ^ (col >> 4)) & 3;
}

// ---------------------------------------------------------------------------
// prep: [0,512) split_x | [512,9728) split_w | [9728,10752) split_pw |
//       [10752,10884) zero Skv+sk | 10884: G transpose+split
// ---------------------------------------------------------------------------
__global__ __launch_bounds__(256) void prep_kernel(
    const float* __restrict__ x,
    const float* __restrict__ qw, const float* __restrict__ kw,
    const float* __restrict__ vw, const float* __restrict__ pw,
    const float* __restrict__ G1q, const float* __restrict__ G2q,
    const float* __restrict__ G1k, const float* __restrict__ G2k,
    __bf16* __restrict__ xTh, __bf16* __restrict__ xTl,
    __bf16* __restrict__ Wrh, __bf16* __restrict__ Wrl,
    __bf16* __restrict__ pwh, __bf16* __restrict__ pwl,
    __bf16* __restrict__ GTh, __bf16* __restrict__ GTl,
    float* __restrict__ Skv)
{
    const int bid = blockIdx.x;
    const int tid = threadIdx.x;
    if (bid < 512) {
        __shared__ float tile[64][65];
        const int lblk = bid & 31, cblk = (bid >> 5) & 7, b = bid >> 8;
        const int l0 = lblk * 64, c0 = cblk * 64;
        #pragma unroll
        for (int it = 0; it < 4; ++it) {
            int cl = (tid >> 4) + it * 16;
            int ll = (tid & 15) * 4;
            float4 v4 = *reinterpret_cast<const float4*>(
                x + ((size_t)b * DIMC + c0 + cl) * LEN + l0 + ll);
            tile[cl][ll+0] = v4.x; tile[cl][ll+1] = v4.y;
            tile[cl][ll+2] = v4.z; tile[cl][ll+3] = v4.w;
        }
        __syncthreads();
        const int l  = tid & 63;
        const int cs = (tid >> 6) * 16;
        size_t rowbase = ((size_t)b * 2050 + l0 + l + 2) * DIMC + c0;
        #pragma unroll
        for (int half = 0; half < 2; ++half) {
            int c = cs + half * 8;
            bf8_t hi, lo;
            #pragma unroll
            for (int e = 0; e < 8; ++e) {
                float f = tile[c + e][l];
                __bf16 h = (__bf16)f;
                hi[e] = h;
                lo[e] = (__bf16)(f - (float)h);
            }
            *reinterpret_cast<bf8_t*>(xTh + rowbase + c) = hi;
            *reinterpret_cast<bf8_t*>(xTl + rowbase + c) = lo;
        }
        if (lblk == 0 && cblk == 0) {
            size_t pb = (size_t)b * 2050 * DIMC;
            #pragma unroll
            for (int e = 0; e < 4; ++e) {
                int p = tid * 4 + e;  // 1024 = 2 pad rows * 512
                xTh[pb + p] = (__bf16)0.f;
                xTl[pb + p] = (__bf16)0.f;
            }
        }
    } else if (bid < 9728) {
        int idx = (bid - 512) * 256 + tid;   // < 1536*1536
        int m   = idx / 1536;
        int rem = idx - m * 1536;
        int kk  = rem >> 9;
        int ci  = rem & 511;
        float f;
        if (m < 512)       f = qw[((size_t)m * 512 + ci) * 3 + kk];
        else if (m < 1024) f = kw[((size_t)(m - 512) * 512 + ci) * 3 + kk];
        else               f = (kk == 2) ? vw[(size_t)(m - 1024) * 512 + ci] : 0.f;
        __bf16 h = (__bf16)f;
        Wrh[idx] = h;
        Wrl[idx] = (__bf16)(f - (float)h);
    } else if (bid < 10752) {
        int idx = (bid - 9728) * 256 + tid;  // < 512*512
        float f = pw[idx];
        __bf16 h = (__bf16)f;
        pwh[idx] = h;
        pwl[idx] = (__bf16)(f - (float)h);
    } else if (bid < 10884) {
        int idx = (bid - 10752) * 256 + tid;
        if (idx < 33792) Skv[idx] = 0.f;
    } else {
        #pragma unroll
        for (int m = 0; m < 4; ++m) {
            const float* g = (m == 0) ? G1q : (m == 1) ? G2q : (m == 2) ? G1k : G2k;
            #pragma unroll
            for (int e = 0; e < 4; ++e) {
                int i = tid * 4 + e;      // 0..1023
                int r = i >> 5, d = i & 31;
                float f = g[d * 32 + r];
                __bf16 h = (__bf16)f;
                GTh[m * 1024 + i] = h;
                GTl[m * 1024 + i] = (__bf16)(f - (float)h);
            }
        }
    }
}

// ---------------------------------------------------------------------------
// conv_mfma: C[mg][l] = sum_kk sum_ci Wr[mg][kk][ci] * xT[l+kk][ci]  (+bias)
// single launch: y 0-3 q, 4-7 k, 8-11 v (kk=2 slice only).
// ---------------------------------------------------------------------------
__global__ __launch_bounds__(256) void conv_mfma_kernel(
    const __bf16* __restrict__ xTh, const __bf16* __restrict__ xTl,
    const __bf16* __restrict__ Wrh, const __bf16* __restrict__ Wrl,
    const float* __restrict__ q_b, const float* __restrict__ k_b,
    float* __restrict__ q, float* __restrict__ k, float* __restrict__ v)
{
    __shared__ __bf16 sAh[128 * 32], sAl[128 * 32], sBh[64 * 32], sBl[64 * 32];
    const int b   = blockIdx.z;
    const int mg  = blockIdx.y * 128;
    const int n0  = blockIdx.x * 64;
    const int tid = threadIdx.x;
    const int wave = tid >> 6, lane = tid & 63;
    const int wm = wave >> 1, wn = wave & 1;
    const int lr = lane & 15, k8 = lane >> 4;
    const int sec = mg >> 9;       // 0:q 1:k 2:v
    const int kks = (sec == 2) ? 2 : 0;

    const __bf16* xh = xTh + (size_t)b * 2050 * DIMC;
    const __bf16* xl = xTl + (size_t)b * 2050 * DIMC;

    f4_t acc[4][2];
    #pragma unroll
    for (int i = 0; i < 4; ++i)
        #pragma unroll
        for (int j = 0; j < 2; ++j)
            #pragma unroll
            for (int e = 0; e < 4; ++e) acc[i][j][e] = 0.f;

    const int sr0 = tid >> 2;
    const int ss  = tid & 3;
    const int sk0 = ((ss ^ ((sr0 >> 1) & 3)) << 3);
    const int sr1 = sr0 + 64;
    const int sk1 = ((ss ^ ((sr1 >> 1) & 3)) << 3);

    for (int kk = kks; kk < 3; ++kk) {
        const __bf16* wAh = Wrh + (size_t)mg * 1536 + kk * 512;
        const __bf16* wAl = Wrl + (size_t)mg * 1536 + kk * 512;
        const __bf16* xbh = xh + (size_t)(n0 + kk) * DIMC;
        const __bf16* xbl = xl + (size_t)(n0 + kk) * DIMC;
        for (int k0 = 0; k0 < 512; k0 += 32) {
            gload16(wAh + (size_t)sr0 * 1536 + k0 + sk0, (char*)sAh + tid * 16);
            gload16(wAh + (size_t)sr1 * 1536 + k0 + sk1, (char*)sAh + (256 + tid) * 16);
            gload16(wAl + (size_t)sr0 * 1536 + k0 + sk0, (char*)sAl + tid * 16);
            gload16(wAl + (size_t)sr1 * 1536 + k0 + sk1, (char*)sAl + (256 + tid) * 16);
            gload16(xbh + (size_t)sr0 * DIMC + k0 + sk0, (char*)sBh + tid * 16);
            gload16(xbl + (size_t)sr0 * DIMC + k0 + sk0, (char*)sBl + tid * 16);
            __syncthreads();
            bf8_t ah[4], al[4], bh[2], bl[2];
            #pragma unroll
            for (int i = 0; i < 4; ++i) {
                int row = wm * 64 + i * 16 + lr;
                int off = row * 64 + ((k8 ^ ((row >> 1) & 3)) << 4);
                ah[i] = *(const bf8_t*)((const char*)sAh + off);
                al[i] = *(const bf8_t*)((const char*)sAl + off);
            }
            #pragma unroll
            for (int j = 0; j < 2; ++j) {
                int row = wn * 32 + j * 16 + lr;
                int off = row * 64 + ((k8 ^ ((row >> 1) & 3)) << 4);
                bh[j] = *(const bf8_t*)((const char*)sBh + off);
                bl[j] = *(const bf8_t*)((const char*)sBl + off);
            }
            #pragma unroll
            for (int i = 0; i < 4; ++i)
                #pragma unroll
                for (int j = 0; j < 2; ++j) {
                    acc[i][j] = __builtin_amdgcn_mfma_f32_16x16x32_bf16(ah[i], bh[j], acc[i][j], 0, 0, 0);
                    acc[i][j] = __builtin_amdgcn_mfma_f32_16x16x32_bf16(ah[i], bl[j], acc[i][j], 0, 0, 0);
                    acc[i][j] = __builtin_amdgcn_mfma_f32_16x16x32_bf16(al[i], bh[j], acc[i][j], 0, 0, 0);
                }
            __syncthreads();
        }
    }
    float* outp = (sec == 0) ? q : (sec == 1) ? k : v;
    const float* bp = (sec == 0) ? q_b : (sec == 1) ? k_b : nullptr;
    const int cob = mg & 511;
    #pragma unroll
    for (int i = 0; i < 4; ++i)
        #pragma unroll
        for (int r = 0; r < 4; ++r) {
            int co = cob + wm * 64 + i * 16 + k8 * 4 + r;
            float bv = bp ? bp[co] : 0.f;
            float* orow = outp + ((size_t)b * DIMC + co) * LEN;
            #pragma unroll
            for (int j = 0; j < 2; ++j)
                orow[n0 + wn * 32 + j * 16 + lr] = acc[i][j][r] + bv;
        }
}

// ---------------------------------------------------------------------------
// sketch_fused: phi = ((q'.G1)*(q'.G2)/sqrt(R))^2 via MFMA (3-term bf16 split).
// isk=0 (q): write phi_q to HBM.  isk=1 (k): keep phi_k in LDS, fuse skv:
//   Skv[r][d] += sum_l phi_k[l][r]*v[d][l];  sk[r] += sum_l phi_k[l][r].
// 2 heads x 64 l per block; z = b + 2*isk.
// ---------------------------------------------------------------------------
__global__ __launch_bounds__(256) void sketch_fused_kernel(
    const float* __restrict__ q, const float* __restrict__ k,
    const float* __restrict__ v,
    const float* __restrict__ gamma_q, const float* __restrict__ beta_q,
    const float* __restrict__ gamma_k, const float* __restrict__ beta_k,
    const __bf16* __restrict__ GTh, const __bf16* __restrict__ GTl,
    float* __restrict__ phi_q, float* __restrict__ Skv, float* __restrict__ sk)
{
    __shared__ __align__(16) char smem[17424];
    __bf16* sBh = (__bf16*)smem;            // phase1: [128 col][32 d] swizzled
    __bf16* sBl = (__bf16*)(smem + 8192);
    const int z = blockIdx.z;
    const int b = z & 1, isk = z >> 1;
    const int h0 = blockIdx.y * 2;
    const int l0 = blockIdx.x * 64;
    const int tid = threadIdx.x;
    const int wave = tid >> 6, lane = tid & 63;
    const int lr = lane & 15, k8 = lane >> 4;

    const float* src = isk ? k : q;
    const float ga = isk ? gamma_k[0] : gamma_q[0];
    const float be = isk ? beta_k[0]  : beta_q[0];

    // stage q' = ga*qk+be as bf16 hi/lo, [col = hloc*64 + l][d], 4-way-max swizzle
    #pragma unroll
    for (int it = 0; it < 4; ++it) {
        int f = it * 256 + tid;          // 0..1023
        int row = f >> 4;                // local channel 0..63
        int l4  = (f & 15) * 4;
        float4 v4 = *reinterpret_cast<const float4*>(
            src + ((size_t)b * DIMC + h0 * 32 + row) * LEN + l0 + l4);
        int d = row & 31, hloc = row >> 5;
        float vv[4] = {v4.x, v4.y, v4.z, v4.w};
        #pragma unroll
        for (int e = 0; e < 4; ++e) {
            float qp = ga * vv[e] + be;
            __bf16 hh = (__bf16)qp;
            int col = hloc * 64 + l4 + e;
            int off = col * 32 + (((d >> 3) ^ fswz(col)) << 3) + (d & 7);
            sBh[off] = hh;
            sBl[off] = (__bf16)(qp - (float)hh);
        }
    }
    __syncthreads();

    const int cw = wave * 32;
    bf8_t bh[2], bl[2];
    #pragma unroll
    for (int nt = 0; nt < 2; ++nt) {
        int col = cw + nt * 16 + lr;
        int off = col * 32 + ((k8 ^ fswz(col)) << 3);
        bh[nt] = *(const bf8_t*)(sBh + off);
        bl[nt] = *(const bf8_t*)(sBl + off);
    }

    const int matb = isk * 2;
    f4_t t1[2][2], t2[2][2];
    #pragma unroll
    for (int mt = 0; mt < 2; ++mt)
        #pragma unroll
        for (int nt = 0; nt < 2; ++nt)
            #pragma unroll
            for (int e = 0; e < 4; ++e) { t1[mt][nt][e] = 0.f; t2[mt][nt][e] = 0.f; }

    #pragma unroll
    for (int mt = 0; mt < 2; ++mt) {
        int abase = matb * 1024 + (mt * 16 + lr) * 32 + k8 * 8;
        bf8_t a1h = *(const bf8_t*)(GTh + abase);
        bf8_t a1l = *(const bf8_t*)(GTl + abase);
        bf8_t a2h = *(const bf8_t*)(GTh + abase + 1024);
        bf8_t a2l = *(const bf8_t*)(GTl + abase + 1024);
        #pragma unroll
        for (int nt = 0; nt < 2; ++nt) {
            t1[mt][nt] = __builtin_amdgcn_mfma_f32_16x16x32_bf16(a1h, bh[nt], t1[mt][nt], 0, 0, 0);
            t1[mt][nt] = __builtin_amdgcn_mfma_f32_16x16x32_bf16(a1h, bl[nt], t1[mt][nt], 0, 0, 0);
            t1[mt][nt] = __builtin_amdgcn_mfma_f32_16x16x32_bf16(a1l, bh[nt], t1[mt][nt], 0, 0, 0);
            t2[mt][nt] = __builtin_amdgcn_mfma_f32_16x16x32_bf16(a2h, bh[nt], t2[mt][nt], 0, 0, 0);
            t2[mt][nt] = __builtin_amdgcn_mfma_f32_16x16x32_bf16(a2h, bl[nt], t2[mt][nt], 0, 0, 0);
            t2[mt][nt] = __builtin_amdgcn_mfma_f32_16x16x32_bf16(a2l, bh[nt], t2[mt][nt], 0, 0, 0);
        }
    }

    if (!isk) {
        // ------- q branch: phi_q -> HBM -------
        #pragma unroll
        for (int mt = 0; mt < 2; ++mt)
            #pragma unroll
            for (int nt = 0; nt < 2; ++nt) {
                int col = cw + nt * 16 + lr;
                int l = col & 63, hloc = col >> 6;
                f4_t out;
                #pragma unroll
                for (int e = 0; e < 4; ++e) {
                    float hh = t1[mt][nt][e] * t2[mt][nt][e] * 0.17677669529663687f;
                    out[e] = hh * hh;
                }
                *reinterpret_cast<f4_t*>(phi_q +
                    (((size_t)b * NH + h0 + hloc) * LEN + l0 + l) * RR + mt * 16 + k8 * 4) = out;
            }
        return;
    }

    // ------- k branch: fused skv (phi_k stays in LDS) -------
    float* phiS = (float*)smem;            // [64][33] fp32 = 8448 B
    float* vS   = (float*)(smem + 8448);   // [64][33] fp32 = 8448 B
    const int r  = tid >> 3;
    const int d4 = (tid & 7) * 4;
    const int hl = wave >> 1;
    #pragma unroll
    for (int hph = 0; hph < 2; ++hph) {
        __syncthreads();   // smem reuse / previous head done
        if (hl == hph) {
            #pragma unroll
            for (int mt = 0; mt < 2; ++mt)
                #pragma unroll
                for (int nt = 0; nt < 2; ++nt) {
                    int l = (cw + nt * 16 + lr) & 63;
                    #pragma unroll
                    for (int e = 0; e < 4; ++e) {
                        float hh = t1[mt][nt][e] * t2[mt][nt][e] * 0.17677669529663687f;
                        phiS[l * 33 + mt * 16 + k8 * 4 + e] = hh * hh;
                    }
                }
        }
        const float* vb = v + ((size_t)b * DIMC + (h0 + hph) * HD) * LEN + l0;
        for (int i = tid; i < 64 * 32; i += 256) {
            int dd = i >> 6, lc = i & 63;
            vS[lc * 33 + dd] = vb[(size_t)dd * LEN + lc];
        }
        __syncthreads();
        float acc4[4] = {0.f, 0.f, 0.f, 0.f};
        float skacc = 0.f;
        #pragma unroll 8
        for (int lc = 0; lc < 64; ++lc) {
            float pv = phiS[lc * 33 + r];
            skacc += pv;
            #pragma unroll
            for (int j = 0; j < 4; ++j) acc4[j] += pv * vS[lc * 33 + d4 + j];
        }
        const size_t base = (size_t)(b * NH + h0 + hph) * RR + r;
        float* Sp = Skv + base * HD + d4;
        #pragma unroll
        for (int j = 0; j < 4; ++j) atomicAdd(Sp + j, acc4[j]);
        if ((tid & 7) == 0) atomicAdd(sk + base, skacc);
    }
}

// ---------------------------------------------------------------------------
// onorm: o[b,l,h*HD+d] = (phi_q . Skv) / (phi_q . sk + 1e-6) -> bf16 hi/lo
// 4 heads x 32 l per block.
// ---------------------------------------------------------------------------
__global__ __launch_bounds__(256) void onorm_kernel(
    const float* __restrict__ phi_q, const float* __restrict__ Skv,
    const float* __restrict__ sk, __bf16* __restrict__ o_h, __bf16* __restrict__ o_l)
{
    __shared__ float Ss[4][RR][HD];
    __shared__ float sks[4][RR];
    __shared__ float ph[32][RR + 1];
    const int b = blockIdx.z, hg = blockIdx.y;
    const int l0 = blockIdx.x * 32;
    const int tid = threadIdx.x;
    const int bh0 = b * NH + hg * 4;
    for (int i = tid; i < 4096; i += 256) {
        int hh = i >> 10;
        Ss[hh][(i >> 5) & 31][i & 31] = Skv[(size_t)(bh0 + hh) * (RR * HD) + (i & 1023)];
    }
    if (tid < 128) sks[tid >> 5][tid & 31] = sk[(size_t)(bh0 + (tid >> 5)) * RR + (tid & 31)];
    const int d = tid & 31, ls = tid >> 5;
    for (int h = 0; h < 4; ++h) {
        __syncthreads();
        for (int i = tid; i < 1024; i += 256)
            ph[i >> 5][i & 31] = phi_q[((size_t)(bh0 + h) * LEN + l0 + (i >> 5)) * RR + (i & 31)];
        __syncthreads();
        #pragma unroll
        for (int lt = 0; lt < 4; ++lt) {
            int l = lt * 8 + ls;
            float num = 0.f, den = 0.f;
            #pragma unroll
            for (int r = 0; r < RR; ++r) {
                float p = ph[l][r];
                num += p * Ss[h][r][d];
                den += p * sks[h][r];
            }
            float val = num / (den + 1e-6f);
            __bf16 hv = (__bf16)val;
            size_t oi = ((size_t)b * LEN + l0 + l) * DIMC + (hg * 4 + h) * HD + d;
            o_h[oi] = hv;
            o_l[oi] = (__bf16)(val - (float)hv);
        }
    }
}

// ---------------------------------------------------------------------------
// proj_mfma: out[m][n] = sum_c o[m][c] pw[n][c] + pb[n];  M=4096 N=512 K=512
// ---------------------------------------------------------------------------
__global__ __launch_bounds__(256) void proj_mfma_kernel(
    const __bf16* __restrict__ oh, const __bf16* __restrict__ ol,
    const __bf16* __restrict__ pwh, const __bf16* __restrict__ pwl,
    const float* __restrict__ pb, float* __restrict__ out)
{
    __shared__ __bf16 sAh[128 * 32], sAl[128 * 32], sBh[64 * 32], sBl[64 * 32];
    const int m0  = blockIdx.y * 128;
    const int n0  = blockIdx.x * 64;
    const int tid = threadIdx.x;
    const int wave = tid >> 6, lane = tid & 63;
    const int wm = wave >> 1, wn = wave & 1;
    const int lr = lane & 15, k8 = lane >> 4;

    f4_t acc[4][2];
    #pragma unroll
    for (int i = 0; i < 4; ++i)
        #pragma unroll
        for (int j = 0; j < 2; ++j)
            #pragma unroll
            for (int e = 0; e < 4; ++e) acc[i][j][e] = 0.f;

    const int sr0 = tid >> 2;
    const int ss  = tid & 3;
    const int sk0 = ((ss ^ ((sr0 >> 1) & 3)) << 3);
    const int sr1 = sr0 + 64;
    const int sk1 = ((ss ^ ((sr1 >> 1) & 3)) << 3);

    for (int k0 = 0; k0 < 512; k0 += 32) {
        gload16(oh + (size_t)(m0 + sr0) * DIMC + k0 + sk0, (char*)sAh + tid * 16);
        gload16(oh + (size_t)(m0 + sr1) * DIMC + k0 + sk1, (char*)sAh + (256 + tid) * 16);
        gload16(ol + (size_t)(m0 + sr0) * DIMC + k0 + sk0, (char*)sAl + tid * 16);
        gload16(ol + (size_t)(m0 + sr1) * DIMC + k0 + sk1, (char*)sAl + (256 + tid) * 16);
        gload16(pwh + (size_t)(n0 + sr0) * DIMC + k0 + sk0, (char*)sBh + tid * 16);
        gload16(pwl + (size_t)(n0 + sr0) * DIMC + k0 + sk0, (char*)sBl + tid * 16);
        __syncthreads();
        bf8_t ah[4], al[4], bh[2], bl[2];
        #pragma unroll
        for (int i = 0; i < 4; ++i) {
            int row = wm * 64 + i * 16 + lr;
            int off = row * 64 + ((k8 ^ ((row >> 1) & 3)) << 4);
            ah[i] = *(const bf8_t*)((const char*)sAh + off);
            al[i] = *(const bf8_t*)((const char*)sAl + off);
        }
        #pragma unroll
        for (int j = 0; j < 2; ++j) {
            int row = wn * 32 + j * 16 + lr;
            int off = row * 64 + ((k8 ^ ((row >> 1) & 3)) << 4);
            bh[j] = *(const bf8_t*)((const char*)sBh + off);
            bl[j] = *(const bf8_t*)((const char*)sBl + off);
        }
        #pragma unroll
        for (int i = 0; i < 4; ++i)
            #pragma unroll
            for (int j = 0; j < 2; ++j) {
                acc[i][j] = __builtin_amdgcn_mfma_f32_16x16x32_bf16(ah[i], bh[j], acc[i][j], 0, 0, 0);
                acc[i][j] = __builtin_amdgcn_mfma_f32_16x16x32_bf16(ah[i], bl[j], acc[i][j], 0, 0, 0);
                acc[i][j] = __builtin_amdgcn_mfma_f32_16x16x32_bf16(al[i], bh[j], acc[i][j], 0, 0, 0);
            }
        __syncthreads();
    }
    #pragma unroll
    for (int j = 0; j < 2; ++j) {
        int n = n0 + wn * 32 + j * 16 + lr;
        float bv = pb[n];
        #pragma unroll
        for (int i = 0; i < 4; ++i)
            #pragma unroll
            for (int r = 0; r < 4; ++r) {
                int m = m0 + wm * 64 + i * 16 + k8 * 4 + r;
                out[(size_t)m * DIMC + n] = acc[i][j][r] + bv;
            }
    }
}

// ---------------------------------------------------------------------------
extern "C" void kernel_launch(void* const* d_in, const int* in_sizes, int n_in,
                              void* d_out, int out_size, void* d_ws, size_t ws_size,
                              hipStream_t stream)
{
    const float* x       = (const float*)d_in[0];
    const float* q_w     = (const float*)d_in[1];
    const float* q_b     = (const float*)d_in[2];
    const float* k_w     = (const float*)d_in[3];
    const float* k_b     = (const float*)d_in[4];
    const float* v_w     = (const float*)d_in[5];
    const float* proj_w  = (const float*)d_in[6];
    const float* proj_b  = (const float*)d_in[7];
    const float* gamma_q = (const float*)d_in[8];
    const float* beta_q  = (const float*)d_in[9];
    const float* gamma_k = (const float*)d_in[10];
    const float* beta_k  = (const float*)d_in[11];
    const float* G1q     = (const float*)d_in[12];
    const float* G2q     = (const float*)d_in[13];
    const float* G1k     = (const float*)d_in[14];
    const float* G2k     = (const float*)d_in[15];

    char* W = (char*)d_ws;
    constexpr size_t QKV  = (size_t)2 * DIMC * LEN * 4;     // 8 MB each
    constexpr size_t XT   = (size_t)2 * 2050 * DIMC * 2;    // 4,198,400 B each
    constexpr size_t WR   = (size_t)1536 * 1536 * 2;        // 4,718,592 B each
    constexpr size_t PW   = (size_t)DIMC * DIMC * 2;        // 524,288 B each
    constexpr size_t GT   = (size_t)4 * 1024 * 2;           // 8,192 B each

    float*  q    = (float*)(W);
    float*  k    = (float*)(W + QKV);
    float*  v    = (float*)(W + 2 * QKV);
    __bf16* xTh  = (__bf16*)(W + 3 * QKV);
    __bf16* xTl  = (__bf16*)(W + 3 * QKV + XT);
    __bf16* Wrh  = (__bf16*)(W + 3 * QKV + 2 * XT);
    __bf16* Wrl  = (__bf16*)(W + 3 * QKV + 2 * XT + WR);
    __bf16* pwh  = (__bf16*)(W + 3 * QKV + 2 * XT + 2 * WR);
    __bf16* pwl  = (__bf16*)(W + 3 * QKV + 2 * XT + 2 * WR + PW);
    __bf16* GTh  = (__bf16*)(W + 3 * QKV + 2 * XT + 2 * WR + 2 * PW);
    __bf16* GTl  = (__bf16*)(W + 3 * QKV + 2 * XT + 2 * WR + 2 * PW + GT);
    float*  Skv  = (float*)(W + 3 * QKV + 2 * XT + 2 * WR + 2 * PW + 2 * GT);
    float*  sk   = Skv + (size_t)2 * NH * RR * HD;
    // aliases (regions dead by the time these are written):
    float*  phi_q = (float*)xTh;          // over xT (8.4 MB >= 8 MB), dead after conv
    __bf16* o_h   = (__bf16*)q;           // over q (dead after sketch)
    __bf16* o_l   = (__bf16*)(W + QKV / 2);

    prep_kernel<<<10885, 256, 0, stream>>>(x, q_w, k_w, v_w, proj_w,
                                           G1q, G2q, G1k, G2k,
                                           xTh, xTl, Wrh, Wrl, pwh, pwl,
                                           GTh, GTl, Skv);

    conv_mfma_kernel<<<dim3(LEN / 64, 12, 2), 256, 0, stream>>>(
        xTh, xTl, Wrh, Wrl, q_b, k_b, q, k, v);

    sketch_fused_kernel<<<dim3(LEN / 64, NH / 2, 4), 256, 0, stream>>>(
        q, k, v, gamma_q, beta_q, gamma_k, beta_k, GTh, GTl, phi_q, Skv, sk);

    onorm_kernel<<<dim3(LEN / 32, NH / 4, 2), 256, 0, stream>>>(
        phi_q, Skv, sk, o_h, o_l);

    proj_mfma_kernel<<<dim3(DIMC / 64, (2 * LEN) / 128), 256, 0, stream>>>(
        o_h, o_l, pwh, pwl, proj_b, (float*)d_out);
}

// Round 10
// 226.873 us; speedup vs baseline: 1.0194x; 1.0194x over previous
//
#include <hip/hip_runtime.h>
#include <hip/hip_bf16.h>

#define DIMC 512
#define LEN  2048
#define NH   16
#define HD   32
#define RR   32

typedef __bf16 bf8_t __attribute__((ext_vector_type(8)));
typedef __bf16 bf4_t __attribute__((ext_vector_type(4)));
typedef float  f4_t  __attribute__((ext_vector_type(4)));

__device__ __forceinline__ void gload16(const void* g, void* l) {
    __builtin_amdgcn_global_load_lds(
        (const __attribute__((address_space(1))) unsigned int*)g,
        (__attribute__((address_space(3))) unsigned int*)l, 16, 0, 0);
}

__device__ __forceinline__ int fswz(int col) {
    return (col ^ (col >> 2) ^ (col >> 4)) & 3;
}

// ---------------------------------------------------------------------------
// prep: [0,512) split_x | [512,2048) split_w (1 row/block) |
//       [2048,2304) split_pw | [2304,2436) zero Skv+sk | 2436: G transpose
// ---------------------------------------------------------------------------
__global__ __launch_bounds__(256) void prep_kernel(
    const float* __restrict__ x,
    const float* __restrict__ qw, const float* __restrict__ kw,
    const float* __restrict__ vw, const float* __restrict__ pw,
    const float* __restrict__ G1q, const float* __restrict__ G2q,
    const float* __restrict__ G1k, const float* __restrict__ G2k,
    __bf16* __restrict__ xTh, __bf16* __restrict__ xTl,
    __bf16* __restrict__ Wrh, __bf16* __restrict__ Wrl,
    __bf16* __restrict__ pwh, __bf16* __restrict__ pwl,
    __bf16* __restrict__ GTh, __bf16* __restrict__ GTl,
    float* __restrict__ Skv)
{
    const int bid = blockIdx.x;
    const int tid = threadIdx.x;
    if (bid < 512) {
        // ------- split_x: x[b][ci][L] -> xT[b][l+2][ci] hi/lo -------
        __shared__ float tile[64][65];
        const int lblk = bid & 31, cblk = (bid >> 5) & 7, b = bid >> 8;
        const int l0 = lblk * 64, c0 = cblk * 64;
        #pragma unroll
        for (int it = 0; it < 4; ++it) {
            int cl = (tid >> 4) + it * 16;
            int ll = (tid & 15) * 4;
            float4 v4 = *reinterpret_cast<const float4*>(
                x + ((size_t)b * DIMC + c0 + cl) * LEN + l0 + ll);
            tile[cl][ll+0] = v4.x; tile[cl][ll+1] = v4.y;
            tile[cl][ll+2] = v4.z; tile[cl][ll+3] = v4.w;
        }
        __syncthreads();
        const int l  = tid & 63;
        const int cs = (tid >> 6) * 16;
        size_t rowbase = ((size_t)b * 2050 + l0 + l + 2) * DIMC + c0;
        #pragma unroll
        for (int half = 0; half < 2; ++half) {
            int c = cs + half * 8;
            bf8_t hi, lo;
            #pragma unroll
            for (int e = 0; e < 8; ++e) {
                float f = tile[c + e][l];
                __bf16 h = (__bf16)f;
                hi[e] = h;
                lo[e] = (__bf16)(f - (float)h);
            }
            *reinterpret_cast<bf8_t*>(xTh + rowbase + c) = hi;
            *reinterpret_cast<bf8_t*>(xTl + rowbase + c) = lo;
        }
        if (lblk == 0 && cblk == 0) {
            size_t pb = (size_t)b * 2050 * DIMC;
            #pragma unroll
            for (int e = 0; e < 4; ++e) {
                int p = tid * 4 + e;  // 1024 = 2 pad rows * 512
                xTh[pb + p] = (__bf16)0.f;
                xTl[pb + p] = (__bf16)0.f;
            }
        }
    } else if (bid < 2048) {
        // ------- split_w: one output row m per block, coalesced both sides --
        __shared__ float raw[1536];
        const int m = bid - 512;            // 0..1535
        const float* srow;
        int len;
        if (m < 512)       { srow = qw + (size_t)m * 1536;         len = 1536; }
        else if (m < 1024) { srow = kw + (size_t)(m - 512) * 1536; len = 1536; }
        else               { srow = vw + (size_t)(m - 1024) * 512; len = 512;  }
        for (int i = tid; i < len; i += 256) raw[i] = srow[i];
        __syncthreads();
        const bool isv = (m >= 1024);
        for (int c8 = tid; c8 < 192; c8 += 256) {
            int o   = c8 * 8;               // output offset in row (kk*512+ci)
            int kk  = o >> 9, ci0 = o & 511;
            bf8_t hi, lo;
            #pragma unroll
            for (int e = 0; e < 8; ++e) {
                float f;
                if (!isv) f = raw[(ci0 + e) * 3 + kk];
                else      f = (kk == 2) ? raw[ci0 + e] : 0.f;
                __bf16 h = (__bf16)f;
                hi[e] = h;
                lo[e] = (__bf16)(f - (float)h);
            }
            *reinterpret_cast<bf8_t*>(Wrh + (size_t)m * 1536 + o) = hi;
            *reinterpret_cast<bf8_t*>(Wrl + (size_t)m * 1536 + o) = lo;
        }
    } else if (bid < 2304) {
        // ------- split_pw: float4 -> 2x bf16x4 -------
        int idx = (bid - 2048) * 1024 + tid * 4;   // < 262144
        float4 v4 = *reinterpret_cast<const float4*>(pw + idx);
        float vv[4] = {v4.x, v4.y, v4.z, v4.w};
        bf4_t hi, lo;
        #pragma unroll
        for (int e = 0; e < 4; ++e) {
            __bf16 h = (__bf16)vv[e];
            hi[e] = h;
            lo[e] = (__bf16)(vv[e] - (float)h);
        }
        *reinterpret_cast<bf4_t*>(pwh + idx) = hi;
        *reinterpret_cast<bf4_t*>(pwl + idx) = lo;
    } else if (bid < 2436) {
        // ------- zero Skv + sk (33792 floats) -------
        int idx = (bid - 2304) * 256 + tid;
        Skv[idx] = 0.f;
    } else {
        // ------- GT: G[d][r] fp32 -> GT[mat][r][d] bf16 hi/lo -------
        #pragma unroll
        for (int m = 0; m < 4; ++m) {
            const float* g = (m == 0) ? G1q : (m == 1) ? G2q : (m == 2) ? G1k : G2k;
            #pragma unroll
            for (int e = 0; e < 4; ++e) {
                int i = tid * 4 + e;      // 0..1023
                int r = i >> 5, d = i & 31;
                float f = g[d * 32 + r];
                __bf16 h = (__bf16)f;
                GTh[m * 1024 + i] = h;
                GTl[m * 1024 + i] = (__bf16)(f - (float)h);
            }
        }
    }
}

// ---------------------------------------------------------------------------
// conv_mfma: C[mg][l] = sum_kk sum_ci Wr[mg][kk][ci] * xT[l+kk][ci]  (+bias)
// single launch: y 0-3 q, 4-7 k, 8-11 v (kk=2 slice only).
// ---------------------------------------------------------------------------
__global__ __launch_bounds__(256) void conv_mfma_kernel(
    const __bf16* __restrict__ xTh, const __bf16* __restrict__ xTl,
    const __bf16* __restrict__ Wrh, const __bf16* __restrict__ Wrl,
    const float* __restrict__ q_b, const float* __restrict__ k_b,
    float* __restrict__ q, float* __restrict__ k, float* __restrict__ v)
{
    __shared__ __bf16 sAh[128 * 32], sAl[128 * 32], sBh[64 * 32], sBl[64 * 32];
    const int b   = blockIdx.z;
    const int mg  = blockIdx.y * 128;
    const int n0  = blockIdx.x * 64;
    const int tid = threadIdx.x;
    const int wave = tid >> 6, lane = tid & 63;
    const int wm = wave >> 1, wn = wave & 1;
    const int lr = lane & 15, k8 = lane >> 4;
    const int sec = mg >> 9;       // 0:q 1:k 2:v
    const int kks = (sec == 2) ? 2 : 0;

    const __bf16* xh = xTh + (size_t)b * 2050 * DIMC;
    const __bf16* xl = xTl + (size_t)b * 2050 * DIMC;

    f4_t acc[4][2];
    #pragma unroll
    for (int i = 0; i < 4; ++i)
        #pragma unroll
        for (int j = 0; j < 2; ++j)
            #pragma unroll
            for (int e = 0; e < 4; ++e) acc[i][j][e] = 0.f;

    const int sr0 = tid >> 2;
    const int ss  = tid & 3;
    const int sk0 = ((ss ^ ((sr0 >> 1) & 3)) << 3);
    const int sr1 = sr0 + 64;
    const int sk1 = ((ss ^ ((sr1 >> 1) & 3)) << 3);

    for (int kk = kks; kk < 3; ++kk) {
        const __bf16* wAh = Wrh + (size_t)mg * 1536 + kk * 512;
        const __bf16* wAl = Wrl + (size_t)mg * 1536 + kk * 512;
        const __bf16* xbh = xh + (size_t)(n0 + kk) * DIMC;
        const __bf16* xbl = xl + (size_t)(n0 + kk) * DIMC;
        for (int k0 = 0; k0 < 512; k0 += 32) {
            gload16(wAh + (size_t)sr0 * 1536 + k0 + sk0, (char*)sAh + tid * 16);
            gload16(wAh + (size_t)sr1 * 1536 + k0 + sk1, (char*)sAh + (256 + tid) * 16);
            gload16(wAl + (size_t)sr0 * 1536 + k0 + sk0, (char*)sAl + tid * 16);
            gload16(wAl + (size_t)sr1 * 1536 + k0 + sk1, (char*)sAl + (256 + tid) * 16);
            gload16(xbh + (size_t)sr0 * DIMC + k0 + sk0, (char*)sBh + tid * 16);
            gload16(xbl + (size_t)sr0 * DIMC + k0 + sk0, (char*)sBl + tid * 16);
            __syncthreads();
            bf8_t ah[4], al[4], bh[2], bl[2];
            #pragma unroll
            for (int i = 0; i < 4; ++i) {
                int row = wm * 64 + i * 16 + lr;
                int off = row * 64 + ((k8 ^ ((row >> 1) & 3)) << 4);
                ah[i] = *(const bf8_t*)((const char*)sAh + off);
                al[i] = *(const bf8_t*)((const char*)sAl + off);
            }
            #pragma unroll
            for (int j = 0; j < 2; ++j) {
                int row = wn * 32 + j * 16 + lr;
                int off = row * 64 + ((k8 ^ ((row >> 1) & 3)) << 4);
                bh[j] = *(const bf8_t*)((const char*)sBh + off);
                bl[j] = *(const bf8_t*)((const char*)sBl + off);
            }
            #pragma unroll
            for (int i = 0; i < 4; ++i)
                #pragma unroll
                for (int j = 0; j < 2; ++j) {
                    acc[i][j] = __builtin_amdgcn_mfma_f32_16x16x32_bf16(ah[i], bh[j], acc[i][j], 0, 0, 0);
                    acc[i][j] = __builtin_amdgcn_mfma_f32_16x16x32_bf16(ah[i], bl[j], acc[i][j], 0, 0, 0);
                    acc[i][j] = __builtin_amdgcn_mfma_f32_16x16x32_bf16(al[i], bh[j], acc[i][j], 0, 0, 0);
                }
            __syncthreads();
        }
    }
    float* outp = (sec == 0) ? q : (sec == 1) ? k : v;
    const float* bp = (sec == 0) ? q_b : (sec == 1) ? k_b : nullptr;
    const int cob = mg & 511;
    #pragma unroll
    for (int i = 0; i < 4; ++i)
        #pragma unroll
        for (int r = 0; r < 4; ++r) {
            int co = cob + wm * 64 + i * 16 + k8 * 4 + r;
            float bv = bp ? bp[co] : 0.f;
            float* orow = outp + ((size_t)b * DIMC + co) * LEN;
            #pragma unroll
            for (int j = 0; j < 2; ++j)
                orow[n0 + wn * 32 + j * 16 + lr] = acc[i][j][r] + bv;
        }
}

// ---------------------------------------------------------------------------
// sketch_fused: phi = ((q'.G1)*(q'.G2)/sqrt(R))^2 via MFMA (3-term bf16 split).
// isk=0 (q): write phi_q to HBM.  isk=1 (k): keep phi_k in LDS, fuse skv.
// 2 heads x 64 l per block; z = b + 2*isk.
// ---------------------------------------------------------------------------
__global__ __launch_bounds__(256) void sketch_fused_kernel(
    const float* __restrict__ q, const float* __restrict__ k,
    const float* __restrict__ v,
    const float* __restrict__ gamma_q, const float* __restrict__ beta_q,
    const float* __restrict__ gamma_k, const float* __restrict__ beta_k,
    const __bf16* __restrict__ GTh, const __bf16* __restrict__ GTl,
    float* __restrict__ phi_q, float* __restrict__ Skv, float* __restrict__ sk)
{
    __shared__ __align__(16) char smem[17424];
    __bf16* sBh = (__bf16*)smem;            // phase1: [128 col][32 d] swizzled
    __bf16* sBl = (__bf16*)(smem + 8192);
    const int z = blockIdx.z;
    const int b = z & 1, isk = z >> 1;
    const int h0 = blockIdx.y * 2;
    const int l0 = blockIdx.x * 64;
    const int tid = threadIdx.x;
    const int wave = tid >> 6, lane = tid & 63;
    const int lr = lane & 15, k8 = lane >> 4;

    const float* src = isk ? k : q;
    const float ga = isk ? gamma_k[0] : gamma_q[0];
    const float be = isk ? beta_k[0]  : beta_q[0];

    #pragma unroll
    for (int it = 0; it < 4; ++it) {
        int f = it * 256 + tid;          // 0..1023
        int row = f >> 4;                // local channel 0..63
        int l4  = (f & 15) * 4;
        float4 v4 = *reinterpret_cast<const float4*>(
            src + ((size_t)b * DIMC + h0 * 32 + row) * LEN + l0 + l4);
        int d = row & 31, hloc = row >> 5;
        float vv[4] = {v4.x, v4.y, v4.z, v4.w};
        #pragma unroll
        for (int e = 0; e < 4; ++e) {
            float qp = ga * vv[e] + be;
            __bf16 hh = (__bf16)qp;
            int col = hloc * 64 + l4 + e;
            int off = col * 32 + (((d >> 3) ^ fswz(col)) << 3) + (d & 7);
            sBh[off] = hh;
            sBl[off] = (__bf16)(qp - (float)hh);
        }
    }
    __syncthreads();

    const int cw = wave * 32;
    bf8_t bh[2], bl[2];
    #pragma unroll
    for (int nt = 0; nt < 2; ++nt) {
        int col = cw + nt * 16 + lr;
        int off = col * 32 + ((k8 ^ fswz(col)) << 3);
        bh[nt] = *(const bf8_t*)(sBh + off);
        bl[nt] = *(const bf8_t*)(sBl + off);
    }

    const int matb = isk * 2;
    f4_t t1[2][2], t2[2][2];
    #pragma unroll
    for (int mt = 0; mt < 2; ++mt)
        #pragma unroll
        for (int nt = 0; nt < 2; ++nt)
            #pragma unroll
            for (int e = 0; e < 4; ++e) { t1[mt][nt][e] = 0.f; t2[mt][nt][e] = 0.f; }

    #pragma unroll
    for (int mt = 0; mt < 2; ++mt) {
        int abase = matb * 1024 + (mt * 16 + lr) * 32 + k8 * 8;
        bf8_t a1h = *(const bf8_t*)(GTh + abase);
        bf8_t a1l = *(const bf8_t*)(GTl + abase);
        bf8_t a2h = *(const bf8_t*)(GTh + abase + 1024);
        bf8_t a2l = *(const bf8_t*)(GTl + abase + 1024);
        #pragma unroll
        for (int nt = 0; nt < 2; ++nt) {
            t1[mt][nt] = __builtin_amdgcn_mfma_f32_16x16x32_bf16(a1h, bh[nt], t1[mt][nt], 0, 0, 0);
            t1[mt][nt] = __builtin_amdgcn_mfma_f32_16x16x32_bf16(a1h, bl[nt], t1[mt][nt], 0, 0, 0);
            t1[mt][nt] = __builtin_amdgcn_mfma_f32_16x16x32_bf16(a1l, bh[nt], t1[mt][nt], 0, 0, 0);
            t2[mt][nt] = __builtin_amdgcn_mfma_f32_16x16x32_bf16(a2h, bh[nt], t2[mt][nt], 0, 0, 0);
            t2[mt][nt] = __builtin_amdgcn_mfma_f32_16x16x32_bf16(a2h, bl[nt], t2[mt][nt], 0, 0, 0);
            t2[mt][nt] = __builtin_amdgcn_mfma_f32_16x16x32_bf16(a2l, bh[nt], t2[mt][nt], 0, 0, 0);
        }
    }

    if (!isk) {
        #pragma unroll
        for (int mt = 0; mt < 2; ++mt)
            #pragma unroll
            for (int nt = 0; nt < 2; ++nt) {
                int col = cw + nt * 16 + lr;
                int l = col & 63, hloc = col >> 6;
                f4_t out;
                #pragma unroll
                for (int e = 0; e < 4; ++e) {
                    float hh = t1[mt][nt][e] * t2[mt][nt][e] * 0.17677669529663687f;
                    out[e] = hh * hh;
                }
                *reinterpret_cast<f4_t*>(phi_q +
                    (((size_t)b * NH + h0 + hloc) * LEN + l0 + l) * RR + mt * 16 + k8 * 4) = out;
            }
        return;
    }

    // ------- k branch: fused skv (phi_k stays in LDS) -------
    float* phiS = (float*)smem;            // [64][33] fp32
    float* vS   = (float*)(smem + 8448);   // [64][33] fp32
    const int r  = tid >> 3;
    const int d4 = (tid & 7) * 4;
    const int hl = wave >> 1;
    #pragma unroll
    for (int hph = 0; hph < 2; ++hph) {
        __syncthreads();
        if (hl == hph) {
            #pragma unroll
            for (int mt = 0; mt < 2; ++mt)
                #pragma unroll
                for (int nt = 0; nt < 2; ++nt) {
                    int l = (cw + nt * 16 + lr) & 63;
                    #pragma unroll
                    for (int e = 0; e < 4; ++e) {
                        float hh = t1[mt][nt][e] * t2[mt][nt][e] * 0.17677669529663687f;
                        phiS[l * 33 + mt * 16 + k8 * 4 + e] = hh * hh;
                    }
                }
        }
        const float* vb = v + ((size_t)b * DIMC + (h0 + hph) * HD) * LEN + l0;
        for (int i = tid; i < 64 * 32; i += 256) {
            int dd = i >> 6, lc = i & 63;
            vS[lc * 33 + dd] = vb[(size_t)dd * LEN + lc];
        }
        __syncthreads();
        float acc4[4] = {0.f, 0.f, 0.f, 0.f};
        float skacc = 0.f;
        #pragma unroll 8
        for (int lc = 0; lc < 64; ++lc) {
            float pv = phiS[lc * 33 + r];
            skacc += pv;
            #pragma unroll
            for (int j = 0; j < 4; ++j) acc4[j] += pv * vS[lc * 33 + d4 + j];
        }
        const size_t base = (size_t)(b * NH + h0 + hph) * RR + r;
        float* Sp = Skv + base * HD + d4;
        #pragma unroll
        for (int j = 0; j < 4; ++j) atomicAdd(Sp + j, acc4[j]);
        if ((tid & 7) == 0) atomicAdd(sk + base, skacc);
    }
}

// ---------------------------------------------------------------------------
// onorm: o[b,l,h*HD+d] = (phi_q . Skv) / (phi_q . sk + 1e-6) -> bf16 hi/lo
// 4 heads x 32 l per block.
// ---------------------------------------------------------------------------
__global__ __launch_bounds__(256) void onorm_kernel(
    const float* __restrict__ phi_q, const float* __restrict__ Skv,
    const float* __restrict__ sk, __bf16* __restrict__ o_h, __bf16* __restrict__ o_l)
{
    __shared__ float Ss[4][RR][HD];
    __shared__ float sks[4][RR];
    __shared__ float ph[32][RR + 1];
    const int b = blockIdx.z, hg = blockIdx.y;
    const int l0 = blockIdx.x * 32;
    const int tid = threadIdx.x;
    const int bh0 = b * NH + hg * 4;
    for (int i = tid; i < 4096; i += 256) {
        int hh = i >> 10;
        Ss[hh][(i >> 5) & 31][i & 31] = Skv[(size_t)(bh0 + hh) * (RR * HD) + (i & 1023)];
    }
    if (tid < 128) sks[tid >> 5][tid & 31] = sk[(size_t)(bh0 + (tid >> 5)) * RR + (tid & 31)];
    const int d = tid & 31, ls = tid >> 5;
    for (int h = 0; h < 4; ++h) {
        __syncthreads();
        for (int i = tid; i < 1024; i += 256)
            ph[i >> 5][i & 31] = phi_q[((size_t)(bh0 + h) * LEN + l0 + (i >> 5)) * RR + (i & 31)];
        __syncthreads();
        #pragma unroll
        for (int lt = 0; lt < 4; ++lt) {
            int l = lt * 8 + ls;
            float num = 0.f, den = 0.f;
            #pragma unroll
            for (int r = 0; r < RR; ++r) {
                float p = ph[l][r];
                num += p * Ss[h][r][d];
                den += p * sks[h][r];
            }
            float val = num / (den + 1e-6f);
            __bf16 hv = (__bf16)val;
            size_t oi = ((size_t)b * LEN + l0 + l) * DIMC + (hg * 4 + h) * HD + d;
            o_h[oi] = hv;
            o_l[oi] = (__bf16)(val - (float)hv);
        }
    }
}

// ---------------------------------------------------------------------------
// proj_mfma: out[m][n] = sum_c o[m][c] pw[n][c] + pb[n];  M=4096 N=512 K=512
// 64x64 tile, 4 waves of 32x32, grid (8,64) = 512 blocks = 2/CU.
// ---------------------------------------------------------------------------
__global__ __launch_bounds__(256) void proj_mfma_kernel(
    const __bf16* __restrict__ oh, const __bf16* __restrict__ ol,
    const __bf16* __restrict__ pwh, const __bf16* __restrict__ pwl,
    const float* __restrict__ pb, float* __restrict__ out)
{
    __shared__ __bf16 sAh[64 * 32], sAl[64 * 32], sBh[64 * 32], sBl[64 * 32];
    const int m0  = blockIdx.y * 64;
    const int n0  = blockIdx.x * 64;
    const int tid = threadIdx.x;
    const int wave = tid >> 6, lane = tid & 63;
    const int wm = wave >> 1, wn = wave & 1;
    const int lr = lane & 15, k8 = lane >> 4;

    f4_t acc[2][2];
    #pragma unroll
    for (int i = 0; i < 2; ++i)
        #pragma unroll
        for (int j = 0; j < 2; ++j)
            #pragma unroll
            for (int e = 0; e < 4; ++e) acc[i][j][e] = 0.f;

    const int sr0 = tid >> 2;
    const int ss  = tid & 3;
    const int sk0 = ((ss ^ ((sr0 >> 1) & 3)) << 3);

    for (int k0 = 0; k0 < 512; k0 += 32) {
        gload16(oh  + (size_t)(m0 + sr0) * DIMC + k0 + sk0, (char*)sAh + tid * 16);
        gload16(ol  + (size_t)(m0 + sr0) * DIMC + k0 + sk0, (char*)sAl + tid * 16);
        gload16(pwh + (size_t)(n0 + sr0) * DIMC + k0 + sk0, (char*)sBh + tid * 16);
        gload16(pwl + (size_t)(n0 + sr0) * DIMC + k0 + sk0, (char*)sBl + tid * 16);
        __syncthreads();
        bf8_t ah[2], al[2], bh[2], bl[2];
        #pragma unroll
        for (int i = 0; i < 2; ++i) {
            int row = wm * 32 + i * 16 + lr;
            int off = row * 64 + ((k8 ^ ((row >> 1) & 3)) << 4);
            ah[i] = *(const bf8_t*)((const char*)sAh + off);
            al[i] = *(const bf8_t*)((const char*)sAl + off);
        }
        #pragma unroll
        for (int j = 0; j < 2; ++j) {
            int row = wn * 32 + j * 16 + lr;
            int off = row * 64 + ((k8 ^ ((row >> 1) & 3)) << 4);
            bh[j] = *(const bf8_t*)((const char*)sBh + off);
            bl[j] = *(const bf8_t*)((const char*)sBl + off);
        }
        #pragma unroll
        for (int i = 0; i < 2; ++i)
            #pragma unroll
            for (int j = 0; j < 2; ++j) {
                acc[i][j] = __builtin_amdgcn_mfma_f32_16x16x32_bf16(ah[i], bh[j], acc[i][j], 0, 0, 0);
                acc[i][j] = __builtin_amdgcn_mfma_f32_16x16x32_bf16(ah[i], bl[j], acc[i][j], 0, 0, 0);
                acc[i][j] = __builtin_amdgcn_mfma_f32_16x16x32_bf16(al[i], bh[j], acc[i][j], 0, 0, 0);
            }
        __syncthreads();
    }
    #pragma unroll
    for (int j = 0; j < 2; ++j) {
        int n = n0 + wn * 32 + j * 16 + lr;
        float bv = pb[n];
        #pragma unroll
        for (int i = 0; i < 2; ++i)
            #pragma unroll
            for (int r = 0; r < 4; ++r) {
                int m = m0 + wm * 32 + i * 16 + k8 * 4 + r;
                out[(size_t)m * DIMC + n] = acc[i][j][r] + bv;
            }
    }
}

// ---------------------------------------------------------------------------
extern "C" void kernel_launch(void* const* d_in, const int* in_sizes, int n_in,
                              void* d_out, int out_size, void* d_ws, size_t ws_size,
                              hipStream_t stream)
{
    const float* x       = (const float*)d_in[0];
    const float* q_w     = (const float*)d_in[1];
    const float* q_b     = (const float*)d_in[2];
    const float* k_w     = (const float*)d_in[3];
    const float* k_b     = (const float*)d_in[4];
    const float* v_w     = (const float*)d_in[5];
    const float* proj_w  = (const float*)d_in[6];
    const float* proj_b  = (const float*)d_in[7];
    const float* gamma_q = (const float*)d_in[8];
    const float* beta_q  = (const float*)d_in[9];
    const float* gamma_k = (const float*)d_in[10];
    const float* beta_k  = (const float*)d_in[11];
    const float* G1q     = (const float*)d_in[12];
    const float* G2q     = (const float*)d_in[13];
    const float* G1k     = (const float*)d_in[14];
    const float* G2k     = (const float*)d_in[15];

    char* W = (char*)d_ws;
    constexpr size_t QKV  = (size_t)2 * DIMC * LEN * 4;     // 8 MB each
    constexpr size_t XT   = (size_t)2 * 2050 * DIMC * 2;    // 4,198,400 B each
    constexpr size_t WR   = (size_t)1536 * 1536 * 2;        // 4,718,592 B each
    constexpr size_t PW   = (size_t)DIMC * DIMC * 2;        // 524,288 B each
    constexpr size_t GT   = (size_t)4 * 1024 * 2;           // 8,192 B each

    float*  q    = (float*)(W);
    float*  k    = (float*)(W + QKV);
    float*  v    = (float*)(W + 2 * QKV);
    __bf16* xTh  = (__bf16*)(W + 3 * QKV);
    __bf16* xTl  = (__bf16*)(W + 3 * QKV + XT);
    __bf16* Wrh  = (__bf16*)(W + 3 * QKV + 2 * XT);
    __bf16* Wrl  = (__bf16*)(W + 3 * QKV + 2 * XT + WR);
    __bf16* pwh  = (__bf16*)(W + 3 * QKV + 2 * XT + 2 * WR);
    __bf16* pwl  = (__bf16*)(W + 3 * QKV + 2 * XT + 2 * WR + PW);
    __bf16* GTh  = (__bf16*)(W + 3 * QKV + 2 * XT + 2 * WR + 2 * PW);
    __bf16* GTl  = (__bf16*)(W + 3 * QKV + 2 * XT + 2 * WR + 2 * PW + GT);
    float*  Skv  = (float*)(W + 3 * QKV + 2 * XT + 2 * WR + 2 * PW + 2 * GT);
    float*  sk   = Skv + (size_t)2 * NH * RR * HD;
    // aliases (regions dead by the time these are written):
    float*  phi_q = (float*)xTh;          // over xT (8.4 MB >= 8 MB), dead after conv
    __bf16* o_h   = (__bf16*)q;           // over q (dead after sketch)
    __bf16* o_l   = (__bf16*)(W + QKV / 2);

    prep_kernel<<<2437, 256, 0, stream>>>(x, q_w, k_w, v_w, proj_w,
                                          G1q, G2q, G1k, G2k,
                                          xTh, xTl, Wrh, Wrl, pwh, pwl,
                                          GTh, GTl, Skv);

    conv_mfma_kernel<<<dim3(LEN / 64, 12, 2), 256, 0, stream>>>(
        xTh, xTl, Wrh, Wrl, q_b, k_b, q, k, v);

    sketch_fused_kernel<<<dim3(LEN / 64, NH / 2, 4), 256, 0, stream>>>(
        q, k, v, gamma_q, beta_q, gamma_k, beta_k, GTh, GTl, phi_q, Skv, sk);

    onorm_kernel<<<dim3(LEN / 32, NH / 4, 2), 256, 0, stream>>>(
        phi_q, Skv, sk, o_h, o_l);

    proj_mfma_kernel<<<dim3(DIMC / 64, (2 * LEN) / 64), 256, 0, stream>>>(
        o_h, o_l, pwh, pwl, proj_b, (float*)d_out);
}

// Round 12
// 225.398 us; speedup vs baseline: 1.0260x; 1.0065x over previous
//
#include <hip/hip_runtime.h>
#include <hip/hip_bf16.h>

#define DIMC 512
#define LEN  2048
#define NH   16
#define HD   32
#define RR   32

typedef __bf16 bf8_t __attribute__((ext_vector_type(8)));
typedef __bf16 bf4_t __attribute__((ext_vector_type(4)));
typedef float  f4_t  __attribute__((ext_vector_type(4)));

__device__ __forceinline__ void gload16(const void* g, void* l) {
    __builtin_amdgcn_global_load_lds(
        (const __attribute__((address_space(1))) unsigned int*)g,
        (__attribute__((address_space(3))) unsigned int*)l, 16, 0, 0);
}

__device__ __forceinline__ int fswz(int col) {
    return (col ^ (col >> 2) ^ (col >> 4)) & 3;
}

// ---------------------------------------------------------------------------
// prep: [0,512) split_x | [512,2048) split_w (1 row/block) |
//       [2048,2304) split_pw | [2304,2436) zero Skv+sk | 2436: G transpose
// ---------------------------------------------------------------------------
__global__ __launch_bounds__(256) void prep_kernel(
    const float* __restrict__ x,
    const float* __restrict__ qw, const float* __restrict__ kw,
    const float* __restrict__ vw, const float* __restrict__ pw,
    const float* __restrict__ G1q, const float* __restrict__ G2q,
    const float* __restrict__ G1k, const float* __restrict__ G2k,
    __bf16* __restrict__ xTh, __bf16* __restrict__ xTl,
    __bf16* __restrict__ Wrh, __bf16* __restrict__ Wrl,
    __bf16* __restrict__ pwh, __bf16* __restrict__ pwl,
    __bf16* __restrict__ GTh, __bf16* __restrict__ GTl,
    float* __restrict__ Skv)
{
    const int bid = blockIdx.x;
    const int tid = threadIdx.x;
    if (bid < 512) {
        // ------- split_x: x[b][ci][L] -> xT[b][l+2][ci] hi/lo -------
        __shared__ float tile[64][65];
        const int lblk = bid & 31, cblk = (bid >> 5) & 7, b = bid >> 8;
        const int l0 = lblk * 64, c0 = cblk * 64;
        #pragma unroll
        for (int it = 0; it < 4; ++it) {
            int cl = (tid >> 4) + it * 16;
            int ll = (tid & 15) * 4;
            float4 v4 = *reinterpret_cast<const float4*>(
                x + ((size_t)b * DIMC + c0 + cl) * LEN + l0 + ll);
            tile[cl][ll+0] = v4.x; tile[cl][ll+1] = v4.y;
            tile[cl][ll+2] = v4.z; tile[cl][ll+3] = v4.w;
        }
        __syncthreads();
        // write: 8 lanes per row -> 128B-contiguous stores
        const int t8 = tid & 7;
        const int rr = tid >> 3;           // 0..31
        #pragma unroll
        for (int half = 0; half < 2; ++half) {
            int row = rr + 32 * half;      // 0..63
            size_t go = ((size_t)b * 2050 + l0 + row + 2) * DIMC + c0 + t8 * 8;
            bf8_t hi, lo;
            #pragma unroll
            for (int e = 0; e < 8; ++e) {
                float f = tile[t8 * 8 + e][row];
                __bf16 h = (__bf16)f;
                hi[e] = h;
                lo[e] = (__bf16)(f - (float)h);
            }
            *reinterpret_cast<bf8_t*>(xTh + go) = hi;
            *reinterpret_cast<bf8_t*>(xTl + go) = lo;
        }
        if (lblk == 0 && cblk == 0) {
            size_t pb = (size_t)b * 2050 * DIMC;
            #pragma unroll
            for (int e = 0; e < 4; ++e) {
                int p = tid * 4 + e;  // 1024 = 2 pad rows * 512
                xTh[pb + p] = (__bf16)0.f;
                xTl[pb + p] = (__bf16)0.f;
            }
        }
    } else if (bid < 2048) {
        // ------- split_w: one output row m per block, coalesced both sides --
        __shared__ float raw[1536];
        const int m = bid - 512;            // 0..1535
        const float* srow;
        int len;
        if (m < 512)       { srow = qw + (size_t)m * 1536;         len = 1536; }
        else if (m < 1024) { srow = kw + (size_t)(m - 512) * 1536; len = 1536; }
        else               { srow = vw + (size_t)(m - 1024) * 512; len = 512;  }
        for (int i = tid; i < len; i += 256) raw[i] = srow[i];
        __syncthreads();
        const bool isv = (m >= 1024);
        for (int c8 = tid; c8 < 192; c8 += 256) {
            int o   = c8 * 8;               // output offset in row (kk*512+ci)
            int kk  = o >> 9, ci0 = o & 511;
            bf8_t hi, lo;
            #pragma unroll
            for (int e = 0; e < 8; ++e) {
                float f;
                if (!isv) f = raw[(ci0 + e) * 3 + kk];
                else      f = (kk == 2) ? raw[ci0 + e] : 0.f;
                __bf16 h = (__bf16)f;
                hi[e] = h;
                lo[e] = (__bf16)(f - (float)h);
            }
            *reinterpret_cast<bf8_t*>(Wrh + (size_t)m * 1536 + o) = hi;
            *reinterpret_cast<bf8_t*>(Wrl + (size_t)m * 1536 + o) = lo;
        }
    } else if (bid < 2304) {
        // ------- split_pw: float4 -> 2x bf16x4 -------
        int idx = (bid - 2048) * 1024 + tid * 4;   // < 262144
        float4 v4 = *reinterpret_cast<const float4*>(pw + idx);
        float vv[4] = {v4.x, v4.y, v4.z, v4.w};
        bf4_t hi, lo;
        #pragma unroll
        for (int e = 0; e < 4; ++e) {
            __bf16 h = (__bf16)vv[e];
            hi[e] = h;
            lo[e] = (__bf16)(vv[e] - (float)h);
        }
        *reinterpret_cast<bf4_t*>(pwh + idx) = hi;
        *reinterpret_cast<bf4_t*>(pwl + idx) = lo;
    } else if (bid < 2436) {
        // ------- zero Skv + sk (33792 floats) -------
        int idx = (bid - 2304) * 256 + tid;
        Skv[idx] = 0.f;
    } else {
        // ------- GT: G[d][r] fp32 -> GT[mat][r][d] bf16 hi/lo -------
        #pragma unroll
        for (int m = 0; m < 4; ++m) {
            const float* g = (m == 0) ? G1q : (m == 1) ? G2q : (m == 2) ? G1k : G2k;
            #pragma unroll
            for (int e = 0; e < 4; ++e) {
                int i = tid * 4 + e;      // 0..1023
                int r = i >> 5, d = i & 31;
                float f = g[d * 32 + r];
                __bf16 h = (__bf16)f;
                GTh[m * 1024 + i] = h;
                GTl[m * 1024 + i] = (__bf16)(f - (float)h);
            }
        }
    }
}

// ---------------------------------------------------------------------------
// fused_qkv: y<4: conv q -> sketch -> phi_q.  y>=4: conv k + conv v (own 4
// heads) -> sketch k -> in-LDS skv + atomics.  q/k/v never hit HBM.
// BM=128 BN=64 BK=32; 4 waves of 64x32; bf16x3 split accumulation.
// ---------------------------------------------------------------------------
#define KLOOP(AROWS, KKOFF, ACC)                                               \
    {                                                                          \
        const __bf16* wAh = Wrh + (size_t)(AROWS) * 1536 + (KKOFF) * 512;      \
        const __bf16* wAl = Wrl + (size_t)(AROWS) * 1536 + (KKOFF) * 512;      \
        const __bf16* xbh = xh + (size_t)(n0 + (KKOFF)) * DIMC;                \
        const __bf16* xbl = xl + (size_t)(n0 + (KKOFF)) * DIMC;                \
        for (int k0 = 0; k0 < 512; k0 += 32) {                                 \
            gload16(wAh + (size_t)sr0 * 1536 + k0 + sk0, (char*)sAh + tid * 16);        \
            gload16(wAh + (size_t)sr1 * 1536 + k0 + sk1, (char*)sAh + (256 + tid) * 16);\
            gload16(wAl + (size_t)sr0 * 1536 + k0 + sk0, (char*)sAl + tid * 16);        \
            gload16(wAl + (size_t)sr1 * 1536 + k0 + sk1, (char*)sAl + (256 + tid) * 16);\
            gload16(xbh + (size_t)sr0 * DIMC + k0 + sk0, (char*)sBh + tid * 16);        \
            gload16(xbl + (size_t)sr0 * DIMC + k0 + sk0, (char*)sBl + tid * 16);        \
            __syncthreads();                                                   \
            bf8_t ah[4], al[4], bh[2], bl[2];                                  \
            _Pragma("unroll")                                                  \
            for (int i = 0; i < 4; ++i) {                                      \
                int row = wm * 64 + i * 16 + lr;                               \
                int off = row * 64 + ((k8 ^ ((row >> 1) & 3)) << 4);           \
                ah[i] = *(const bf8_t*)((const char*)sAh + off);               \
                al[i] = *(const bf8_t*)((const char*)sAl + off);               \
            }                                                                  \
            _Pragma("unroll")                                                  \
            for (int j = 0; j < 2; ++j) {                                      \
                int row = wn * 32 + j * 16 + lr;                               \
                int off = row * 64 + ((k8 ^ ((row >> 1) & 3)) << 4);           \
                bh[j] = *(const bf8_t*)((const char*)sBh + off);               \
                bl[j] = *(const bf8_t*)((const char*)sBl + off);               \
            }                                                                  \
            _Pragma("unroll")                                                  \
            for (int i = 0; i < 4; ++i)                                        \
                _Pragma("unroll")                                              \
                for (int j = 0; j < 2; ++j) {                                  \
                    ACC[i][j] = __builtin_amdgcn_mfma_f32_16x16x32_bf16(ah[i], bh[j], ACC[i][j], 0, 0, 0); \
                    ACC[i][j] = __builtin_amdgcn_mfma_f32_16x16x32_bf16(ah[i], bl[j], ACC[i][j], 0, 0, 0); \
                    ACC[i][j] = __builtin_amdgcn_mfma_f32_16x16x32_bf16(al[i], bh[j], ACC[i][j], 0, 0, 0); \
                }                                                              \
            __syncthreads();                                                   \
        }                                                                      \
    }

__global__ __launch_bounds__(256) void fused_qkv_kernel(
    const __bf16* __restrict__ xTh, const __bf16* __restrict__ xTl,
    const __bf16* __restrict__ Wrh, const __bf16* __restrict__ Wrl,
    const float* __restrict__ q_b, const float* __restrict__ k_b,
    const float* __restrict__ gamma_q, const float* __restrict__ beta_q,
    const float* __restrict__ gamma_k, const float* __restrict__ beta_k,
    const __bf16* __restrict__ GTh, const __bf16* __restrict__ GTl,
    float* __restrict__ phi_q, float* __restrict__ Skv, float* __restrict__ sk)
{
    __shared__ __align__(16) char smem[24576];
    __bf16* sAh = (__bf16*)smem;
    __bf16* sAl = (__bf16*)(smem + 8192);
    __bf16* sBh = (__bf16*)(smem + 16384);
    __bf16* sBl = (__bf16*)(smem + 20480);

    const int b   = blockIdx.z;
    const int ys  = blockIdx.y;          // 0..7
    const int isk = ys >> 2;             // 0:q 1:k(+v)
    const int cob = (ys & 3) * 128;
    const int n0  = blockIdx.x * 64;
    const int tid = threadIdx.x;
    const int wave = tid >> 6, lane = tid & 63;
    const int wm = wave >> 1, wn = wave & 1;
    const int lr = lane & 15, k8 = lane >> 4;

    const __bf16* xh = xTh + (size_t)b * 2050 * DIMC;
    const __bf16* xl = xTl + (size_t)b * 2050 * DIMC;

    f4_t acc[4][2], accv[4][2];
    #pragma unroll
    for (int i = 0; i < 4; ++i)
        #pragma unroll
        for (int j = 0; j < 2; ++j)
            #pragma unroll
            for (int e = 0; e < 4; ++e) { acc[i][j][e] = 0.f; accv[i][j][e] = 0.f; }

    const int sr0 = tid >> 2;
    const int ss  = tid & 3;
    const int sk0 = ((ss ^ ((sr0 >> 1) & 3)) << 3);
    const int sr1 = sr0 + 64;
    const int sk1 = ((ss ^ ((sr1 >> 1) & 3)) << 3);

    const int mg = isk * 512 + cob;
    for (int kk = 0; kk < 3; ++kk) KLOOP(mg, kk, acc);
    if (isk) KLOOP(1024 + cob, 2, accv);

    // ---------------- sketch (+skv) epilogue ----------------
    const float ga = isk ? gamma_k[0] : gamma_q[0];
    const float be = isk ? beta_k[0]  : beta_q[0];
    const float* bp = isk ? k_b : q_b;
    const int h0 = cob >> 5;
    const int matb = isk * 2;
    __bf16* skh = (__bf16*)smem;
    __bf16* skl = (__bf16*)(smem + 8192);
    float* phiS = (float*)smem;            // [64][33] fp32
    float* vS   = (float*)(smem + 8448);   // [64][33] fp32

    #pragma unroll
    for (int p = 0; p < 2; ++p) {
        __syncthreads();
        // stage q'/k' (heads 2p..2p+1) bf16 hi/lo from acc, swizzled
        if (wm == p) {
            #pragma unroll
            for (int i = 0; i < 4; ++i) {
                const int hloc = i >> 1;
                #pragma unroll
                for (int r = 0; r < 4; ++r) {
                    int cl = i * 16 + k8 * 4 + r;      // 0..63 within pair
                    int d  = cl & 31;
                    float bv = bp[cob + p * 64 + cl];
                    #pragma unroll
                    for (int j = 0; j < 2; ++j) {
                        float qp = ga * (acc[i][j][r] + bv) + be;
                        __bf16 hh = (__bf16)qp;
                        int col = hloc * 64 + wn * 32 + j * 16 + lr;
                        int off = col * 32 + (((d >> 3) ^ fswz(col)) << 3) + (d & 7);
                        skh[off] = hh;
                        skl[off] = (__bf16)(qp - (float)hh);
                    }
                }
            }
        }
        __syncthreads();
        const int cw = wave * 32;
        bf8_t bhf[2], blf[2];
        #pragma unroll
        for (int nt = 0; nt < 2; ++nt) {
            int col = cw + nt * 16 + lr;
            int off = col * 32 + ((k8 ^ fswz(col)) << 3);
            bhf[nt] = *(const bf8_t*)(skh + off);
            blf[nt] = *(const bf8_t*)(skl + off);
        }
        f4_t t1[2][2], t2[2][2];
        #pragma unroll
        for (int mt = 0; mt < 2; ++mt)
            #pragma unroll
            for (int nt = 0; nt < 2; ++nt)
                #pragma unroll
                for (int e = 0; e < 4; ++e) { t1[mt][nt][e] = 0.f; t2[mt][nt][e] = 0.f; }
        #pragma unroll
        for (int mt = 0; mt < 2; ++mt) {
            int abase = matb * 1024 + (mt * 16 + lr) * 32 + k8 * 8;
            bf8_t a1h = *(const bf8_t*)(GTh + abase);
            bf8_t a1l = *(const bf8_t*)(GTl + abase);
            bf8_t a2h = *(const bf8_t*)(GTh + abase + 1024);
            bf8_t a2l = *(const bf8_t*)(GTl + abase + 1024);
            #pragma unroll
            for (int nt = 0; nt < 2; ++nt) {
                t1[mt][nt] = __builtin_amdgcn_mfma_f32_16x16x32_bf16(a1h, bhf[nt], t1[mt][nt], 0, 0, 0);
                t1[mt][nt] = __builtin_amdgcn_mfma_f32_16x16x32_bf16(a1h, blf[nt], t1[mt][nt], 0, 0, 0);
                t1[mt][nt] = __builtin_amdgcn_mfma_f32_16x16x32_bf16(a1l, bhf[nt], t1[mt][nt], 0, 0, 0);
                t2[mt][nt] = __builtin_amdgcn_mfma_f32_16x16x32_bf16(a2h, bhf[nt], t2[mt][nt], 0, 0, 0);
                t2[mt][nt] = __builtin_amdgcn_mfma_f32_16x16x32_bf16(a2h, blf[nt], t2[mt][nt], 0, 0, 0);
                t2[mt][nt] = __builtin_amdgcn_mfma_f32_16x16x32_bf16(a2l, bhf[nt], t2[mt][nt], 0, 0, 0);
            }
        }

        if (!isk) {
            // ------- q: phi_q -> HBM -------
            #pragma unroll
            for (int mt = 0; mt < 2; ++mt)
                #pragma unroll
                for (int nt = 0; nt < 2; ++nt) {
                    int col = cw + nt * 16 + lr;
                    int l = col & 63, hloc = col >> 6;
                    f4_t out;
                    #pragma unroll
                    for (int e = 0; e < 4; ++e) {
                        float hh = t1[mt][nt][e] * t2[mt][nt][e] * 0.17677669529663687f;
                        out[e] = hh * hh;
                    }
                    *reinterpret_cast<f4_t*>(phi_q +
                        (((size_t)b * NH + h0 + 2 * p + hloc) * LEN + n0 + l) * RR + mt * 16 + k8 * 4) = out;
                }
        } else {
            // ------- k: fused skv (phi_k + v stay on-chip) -------
            #pragma unroll
            for (int hph = 0; hph < 2; ++hph) {
                __syncthreads();
                if (wm == hph) {
                    // stage phi for head 2p+hph (these waves own its columns)
                    #pragma unroll
                    for (int mt = 0; mt < 2; ++mt)
                        #pragma unroll
                        for (int nt = 0; nt < 2; ++nt) {
                            int col = cw + nt * 16 + lr;
                            int l = col & 63;
                            #pragma unroll
                            for (int e = 0; e < 4; ++e) {
                                float hh = t1[mt][nt][e] * t2[mt][nt][e] * 0.17677669529663687f;
                                phiS[l * 33 + mt * 16 + k8 * 4 + e] = hh * hh;
                            }
                        }
                }
                if (wm == p) {
                    // stage v for head 2p+hph from accv
                    #pragma unroll
                    for (int ii = 0; ii < 2; ++ii)
                        #pragma unroll
                        for (int j = 0; j < 2; ++j)
                            #pragma unroll
                            for (int r = 0; r < 4; ++r) {
                                int d = ii * 16 + k8 * 4 + r;
                                int l = wn * 32 + j * 16 + lr;
                                vS[l * 33 + d] = accv[2 * hph + ii][j][r];
                            }
                }
                __syncthreads();
                const int r2 = tid >> 3;
                const int d4 = (tid & 7) * 4;
                float a4[4] = {0.f, 0.f, 0.f, 0.f};
                float ska = 0.f;
                #pragma unroll 8
                for (int lc = 0; lc < 64; ++lc) {
                    float pv = phiS[lc * 33 + r2];
                    ska += pv;
                    #pragma unroll
                    for (int j = 0; j < 4; ++j) a4[j] += pv * vS[lc * 33 + d4 + j];
                }
                const size_t base = (size_t)(b * NH + h0 + 2 * p + hph) * RR + r2;
                float* Sp = Skv + base * HD + d4;
                #pragma unroll
                for (int j = 0; j < 4; ++j) atomicAdd(Sp + j, a4[j]);
                if ((tid & 7) == 0) atomicAdd(sk + base, ska);
            }
        }
    }
}

// ---------------------------------------------------------------------------
// onorm: o[b,l,h*HD+d] = (phi_q . Skv) / (phi_q . sk + 1e-6) -> bf16 hi/lo
// ---------------------------------------------------------------------------
__global__ __launch_bounds__(256) void onorm_kernel(
    const float* __restrict__ phi_q, const float* __restrict__ Skv,
    const float* __restrict__ sk, __bf16* __restrict__ o_h, __bf16* __restrict__ o_l)
{
    __shared__ float Ss[4][RR][HD];
    __shared__ float sks[4][RR];
    __shared__ float ph[32][RR + 1];
    const int b = blockIdx.z, hg = blockIdx.y;
    const int l0 = blockIdx.x * 32;
    const int tid = threadIdx.x;
    const int bh0 = b * NH + hg * 4;
    for (int i = tid; i < 4096; i += 256) {
        int hh = i >> 10;
        Ss[hh][(i >> 5) & 31][i & 31] = Skv[(size_t)(bh0 + hh) * (RR * HD) + (i & 1023)];
    }
    if (tid < 128) sks[tid >> 5][tid & 31] = sk[(size_t)(bh0 + (tid >> 5)) * RR + (tid & 31)];
    const int d = tid & 31, ls = tid >> 5;
    for (int h = 0; h < 4; ++h) {
        __syncthreads();
        for (int i = tid; i < 1024; i += 256)
            ph[i >> 5][i & 31] = phi_q[((size_t)(bh0 + h) * LEN + l0 + (i >> 5)) * RR + (i & 31)];
        __syncthreads();
        #pragma unroll
        for (int lt = 0; lt < 4; ++lt) {
            int l = lt * 8 + ls;
            float num = 0.f, den = 0.f;
            #pragma unroll
            for (int r = 0; r < RR; ++r) {
                float p = ph[l][r];
                num += p * Ss[h][r][d];
                den += p * sks[h][r];
            }
            float val = num / (den + 1e-6f);
            __bf16 hv = (__bf16)val;
            size_t oi = ((size_t)b * LEN + l0 + l) * DIMC + (hg * 4 + h) * HD + d;
            o_h[oi] = hv;
            o_l[oi] = (__bf16)(val - (float)hv);
        }
    }
}

// ---------------------------------------------------------------------------
// proj_mfma: out[m][n] = sum_c o[m][c] pw[n][c] + pb[n];  M=4096 N=512 K=512
// 64x64 tile, 4 waves of 32x32, grid (8,64) = 512 blocks = 2/CU.
// ---------------------------------------------------------------------------
__global__ __launch_bounds__(256) void proj_mfma_kernel(
    const __bf16* __restrict__ oh, const __bf16* __restrict__ ol,
    const __bf16* __restrict__ pwh, const __bf16* __restrict__ pwl,
    const float* __restrict__ pb, float* __restrict__ out)
{
    __shared__ __bf16 sAh[64 * 32], sAl[64 * 32], sBh[64 * 32], sBl[64 * 32];
    const int m0  = blockIdx.y * 64;
    const int n0  = blockIdx.x * 64;
    const int tid = threadIdx.x;
    const int wave = tid >> 6, lane = tid & 63;
    const int wm = wave >> 1, wn = wave & 1;
    const int lr = lane & 15, k8 = lane >> 4;

    f4_t acc[2][2];
    #pragma unroll
    for (int i = 0; i < 2; ++i)
        #pragma unroll
        for (int j = 0; j < 2; ++j)
            #pragma unroll
            for (int e = 0; e < 4; ++e) acc[i][j][e] = 0.f;

    const int sr0 = tid >> 2;
    const int ss  = tid & 3;
    const int sk0 = ((ss ^ ((sr0 >> 1) & 3)) << 3);

    for (int k0 = 0; k0 < 512; k0 += 32) {
        gload16(oh  + (size_t)(m0 + sr0) * DIMC + k0 + sk0, (char*)sAh + tid * 16);
        gload16(ol  + (size_t)(m0 + sr0) * DIMC + k0 + sk0, (char*)sAl + tid * 16);
        gload16(pwh + (size_t)(n0 + sr0) * DIMC + k0 + sk0, (char*)sBh + tid * 16);
        gload16(pwl + (size_t)(n0 + sr0) * DIMC + k0 + sk0, (char*)sBl + tid * 16);
        __syncthreads();
        bf8_t ah[2], al[2], bh[2], bl[2];
        #pragma unroll
        for (int i = 0; i < 2; ++i) {
            int row = wm * 32 + i * 16 + lr;
            int off = row * 64 + ((k8 ^ ((row >> 1) & 3)) << 4);
            ah[i] = *(const bf8_t*)((const char*)sAh + off);
            al[i] = *(const bf8_t*)((const char*)sAl + off);
        }
        #pragma unroll
        for (int j = 0; j < 2; ++j) {
            int row = wn * 32 + j * 16 + lr;
            int off = row * 64 + ((k8 ^ ((row >> 1) & 3)) << 4);
            bh[j] = *(const bf8_t*)((const char*)sBh + off);
            bl[j] = *(const bf8_t*)((const char*)sBl + off);
        }
        #pragma unroll
        for (int i = 0; i < 2; ++i)
            #pragma unroll
            for (int j = 0; j < 2; ++j) {
                acc[i][j] = __builtin_amdgcn_mfma_f32_16x16x32_bf16(ah[i], bh[j], acc[i][j], 0, 0, 0);
                acc[i][j] = __builtin_amdgcn_mfma_f32_16x16x32_bf16(ah[i], bl[j], acc[i][j], 0, 0, 0);
                acc[i][j] = __builtin_amdgcn_mfma_f32_16x16x32_bf16(al[i], bh[j], acc[i][j], 0, 0, 0);
            }
        __syncthreads();
    }
    #pragma unroll
    for (int j = 0; j < 2; ++j) {
        int n = n0 + wn * 32 + j * 16 + lr;
        float bv = pb[n];
        #pragma unroll
        for (int i = 0; i < 2; ++i)
            #pragma unroll
            for (int r = 0; r < 4; ++r) {
                int m = m0 + wm * 32 + i * 16 + k8 * 4 + r;
                out[(size_t)m * DIMC + n] = acc[i][j][r] + bv;
            }
    }
}

// ---------------------------------------------------------------------------
extern "C" void kernel_launch(void* const* d_in, const int* in_sizes, int n_in,
                              void* d_out, int out_size, void* d_ws, size_t ws_size,
                              hipStream_t stream)
{
    const float* x       = (const float*)d_in[0];
    const float* q_w     = (const float*)d_in[1];
    const float* q_b     = (const float*)d_in[2];
    const float* k_w     = (const float*)d_in[3];
    const float* k_b     = (const float*)d_in[4];
    const float* v_w     = (const float*)d_in[5];
    const float* proj_w  = (const float*)d_in[6];
    const float* proj_b  = (const float*)d_in[7];
    const float* gamma_q = (const float*)d_in[8];
    const float* beta_q  = (const float*)d_in[9];
    const float* gamma_k = (const float*)d_in[10];
    const float* beta_k  = (const float*)d_in[11];
    const float* G1q     = (const float*)d_in[12];
    const float* G2q     = (const float*)d_in[13];
    const float* G1k     = (const float*)d_in[14];
    const float* G2k     = (const float*)d_in[15];

    char* W = (char*)d_ws;
    constexpr size_t XT   = (size_t)2 * 2050 * DIMC * 2;    // 4,198,400 B each
    constexpr size_t WR   = (size_t)1536 * 1536 * 2;        // 4,718,592 B each
    constexpr size_t PW   = (size_t)DIMC * DIMC * 2;        // 524,288 B each
    constexpr size_t GT   = (size_t)4 * 1024 * 2;           // 8,192 B each
    constexpr size_t SKVB = (size_t)2 * NH * RR * HD * 4;   // 131,072 B
    constexpr size_t SKB  = (size_t)2 * NH * RR * 4;        // 4,096 B

    __bf16* xTh  = (__bf16*)(W);
    __bf16* xTl  = (__bf16*)(W + XT);
    __bf16* Wrh  = (__bf16*)(W + 2 * XT);
    __bf16* Wrl  = (__bf16*)(W + 2 * XT + WR);
    __bf16* pwh  = (__bf16*)(W + 2 * XT + 2 * WR);
    __bf16* pwl  = (__bf16*)(W + 2 * XT + 2 * WR + PW);
    __bf16* GTh  = (__bf16*)(W + 2 * XT + 2 * WR + 2 * PW);
    __bf16* GTl  = (__bf16*)(W + 2 * XT + 2 * WR + 2 * PW + GT);
    float*  Skv  = (float*)(W + 2 * XT + 2 * WR + 2 * PW + 2 * GT);
    float*  sk   = Skv + (size_t)2 * NH * RR * HD;
    float*  phi_q = (float*)(W + 2 * XT + 2 * WR + 2 * PW + 2 * GT + SKVB + SKB);
    // o (bf16 hi/lo) aliases xT (dead after fused kernel):
    __bf16* o_h  = xTh;
    __bf16* o_l  = xTl;

    prep_kernel<<<2437, 256, 0, stream>>>(x, q_w, k_w, v_w, proj_w,
                                          G1q, G2q, G1k, G2k,
                                          xTh, xTl, Wrh, Wrl, pwh, pwl,
                                          GTh, GTl, Skv);

    fused_qkv_kernel<<<dim3(LEN / 64, 8, 2), 256, 0, stream>>>(
        xTh, xTl, Wrh, Wrl, q_b, k_b, gamma_q, beta_q, gamma_k, beta_k,
        GTh, GTl, phi_q, Skv, sk);

    onorm_kernel<<<dim3(LEN / 32, NH / 4, 2), 256, 0, stream>>>(
        phi_q, Skv, sk, o_h, o_l);

    proj_mfma_kernel<<<dim3(DIMC / 64, (2 * LEN) / 64), 256, 0, stream>>>(
        o_h, o_l, pwh, pwl, proj_b, (float*)d_out);
}